// Round 1
// baseline (1091.990 us; speedup 1.0000x reference)
//
#include <hip/hip_runtime.h>
#include <math.h>

#define K 3
#define K2 9
#define BB 4
#define C 64
#define H 128
#define W 128
#define O 64
#define HW (H*W)
#define Ho 128
#define Wo 128
#define CKK (C*K*K)   // 576

// ---------------------------------------------------------------------------
// Kernel A: per-(b,h,w) thread computes 18 offset channels + mod mean.
// x loads are coalesced along w; weight indices are wave-uniform -> s_loads.
// ---------------------------------------------------------------------------
__global__ __launch_bounds__(256) void offset_mod_kernel(
    const float* __restrict__ x,
    const float* __restrict__ offset_w,
    const float* __restrict__ offset_b,
    const float* __restrict__ mod_w,
    const float* __restrict__ mod_b,
    float* __restrict__ offsets,   // (B, 18, Ho, Wo)
    float* __restrict__ modmean)   // (B, Ho, Wo)
{
    int idx = blockIdx.x * blockDim.x + threadIdx.x;
    if (idx >= BB * Ho * Wo) return;
    int w = idx % Wo;
    int h = (idx / Wo) % Ho;
    int b = idx / (Ho * Wo);

    float acc[27];
    #pragma unroll
    for (int m = 0; m < 18; m++) acc[m] = offset_b[m];
    #pragma unroll
    for (int m = 0; m < 9; m++) acc[18 + m] = mod_b[m];

    const float* xb = x + (size_t)b * C * HW;
    for (int c = 0; c < C; c++) {
        const float* xc = xb + c * HW;
        #pragma unroll
        for (int i = 0; i < K; i++) {
            int yy = h + i - 1;
            if (yy < 0 || yy >= H) continue;
            #pragma unroll
            for (int j = 0; j < K; j++) {
                int xx = w + j - 1;
                if (xx < 0 || xx >= W) continue;
                float v = xc[yy * W + xx];
                int wi = (c * K + i) * K + j;   // index within (C,K,K)
                #pragma unroll
                for (int m = 0; m < 18; m++) acc[m] += v * offset_w[m * CKK + wi];
                #pragma unroll
                for (int m = 0; m < 9; m++) acc[18 + m] += v * mod_w[m * CKK + wi];
            }
        }
    }

    #pragma unroll
    for (int m = 0; m < 18; m++)
        offsets[((b * 18 + m) * Ho + h) * Wo + w] = acc[m];

    float s = 0.f;
    #pragma unroll
    for (int m = 0; m < 9; m++) s += 1.f / (1.f + expf(-acc[18 + m]));
    modmean[(b * Ho + h) * Wo + w] = s * (1.f / 9.f);
}

// ---------------------------------------------------------------------------
// Kernel W: transpose weight (O,C,K2) -> wT (C,K2,O) so the dot-phase weight
// loads are coalesced across lanes (lane = o).
// ---------------------------------------------------------------------------
__global__ void transpose_w_kernel(const float* __restrict__ weight,
                                   float* __restrict__ wT)
{
    int i = blockIdx.x * blockDim.x + threadIdx.x;
    if (i >= O * C * K2) return;
    int k = i % K2;
    int c = (i / K2) % C;
    int o = i / (K2 * C);
    wT[(c * K2 + k) * O + o] = weight[i];
}

// ---------------------------------------------------------------------------
// Kernel B: one 64-thread block per output pixel.
//   phase 1: lanes 0..8 compute bilinear params for the 9 taps -> LDS
//   phase 2: lane = input channel c, gather 9 bilinear samples -> LDS
//   phase 3: lane = output channel o, 576-MAC dot vs wT, scale by modmean.
// ---------------------------------------------------------------------------
__global__ __launch_bounds__(64) void deform_kernel(
    const float* __restrict__ x,
    const float* __restrict__ wT,      // (C, K2, O)
    const float* __restrict__ bias,
    const float* __restrict__ offsets, // (B, 18, Ho, Wo)
    const float* __restrict__ modmean, // (B, Ho, Wo)
    float* __restrict__ out)           // (B, O, Ho, Wo)
{
    __shared__ float s_val[K2 * C];
    __shared__ int   s_y0[K2], s_x0[K2];
    __shared__ float s_wy1[K2], s_wx1[K2];

    int pix = blockIdx.x;
    int w = pix % Wo;
    int h = (pix / Wo) % Ho;
    int b = pix / (Ho * Wo);
    int t = threadIdx.x;

    if (t < K2) {
        int k = t;
        float offy = offsets[((b * 18 + k) * Ho + h) * Wo + w];
        float offx = offsets[((b * 18 + 9 + k) * Ho + h) * Wo + w];
        float sy = (float)h + (float)(k / 3 - 1) + offy;
        float sx = (float)w + (float)(k % 3 - 1) + offx;
        float fy0 = floorf(sy), fx0 = floorf(sx);
        s_y0[k] = (int)fy0;
        s_x0[k] = (int)fx0;
        s_wy1[k] = sy - fy0;
        s_wx1[k] = sx - fx0;
    }
    __syncthreads();

    {
        int c = t;
        const float* xc = x + ((size_t)b * C + c) * HW;
        #pragma unroll
        for (int k = 0; k < K2; k++) {
            int y0 = s_y0[k], x0 = s_x0[k];
            int y1 = y0 + 1, x1 = x0 + 1;
            float wy1 = s_wy1[k], wx1 = s_wx1[k];
            float wy0 = 1.f - wy1, wx0 = 1.f - wx1;
            bool y0v = (y0 >= 0) && (y0 < H);
            bool y1v = (y1 >= 0) && (y1 < H);
            bool x0v = (x0 >= 0) && (x0 < W);
            bool x1v = (x1 >= 0) && (x1 < W);
            float v00 = (y0v && x0v) ? xc[y0 * W + x0] : 0.f;
            float v01 = (y0v && x1v) ? xc[y0 * W + x1] : 0.f;
            float v10 = (y1v && x0v) ? xc[y1 * W + x0] : 0.f;
            float v11 = (y1v && x1v) ? xc[y1 * W + x1] : 0.f;
            s_val[k * C + c] = (v00 * wx0 + v01 * wx1) * wy0
                             + (v10 * wx0 + v11 * wx1) * wy1;
        }
    }
    __syncthreads();

    {
        int o = t;
        float acc = 0.f;
        for (int c = 0; c < C; c++) {
            #pragma unroll
            for (int k = 0; k < K2; k++) {
                acc += s_val[k * C + c] * wT[(c * K2 + k) * O + o];
            }
        }
        float mm = modmean[(b * Ho + h) * Wo + w];
        out[(((size_t)b * O + o) * Ho + h) * Wo + w] = acc * mm + bias[o];
    }
}

extern "C" void kernel_launch(void* const* d_in, const int* in_sizes, int n_in,
                              void* d_out, int out_size, void* d_ws, size_t ws_size,
                              hipStream_t stream) {
    const float* x        = (const float*)d_in[0];
    const float* weight   = (const float*)d_in[1];
    const float* bias     = (const float*)d_in[2];
    const float* offset_w = (const float*)d_in[3];
    const float* offset_b = (const float*)d_in[4];
    const float* mod_w    = (const float*)d_in[5];
    const float* mod_b    = (const float*)d_in[6];
    float* out = (float*)d_out;

    // Workspace layout (floats):
    //   offsets : B*18*Ho*Wo = 1,179,648
    //   modmean : B*Ho*Wo    =    65,536
    //   wT      : C*K2*O     =    36,864
    float* ws_offsets = (float*)d_ws;
    float* ws_modmean = ws_offsets + (size_t)BB * 18 * Ho * Wo;
    float* ws_wT      = ws_modmean + (size_t)BB * Ho * Wo;

    {
        int total = O * C * K2;
        transpose_w_kernel<<<(total + 255) / 256, 256, 0, stream>>>(weight, ws_wT);
    }
    {
        int total = BB * Ho * Wo;
        offset_mod_kernel<<<(total + 255) / 256, 256, 0, stream>>>(
            x, offset_w, offset_b, mod_w, mod_b, ws_offsets, ws_modmean);
    }
    {
        int total = BB * Ho * Wo;   // one block per pixel
        deform_kernel<<<total, 64, 0, stream>>>(
            x, ws_wT, bias, ws_offsets, ws_modmean, out);
    }
}

// Round 2
// 301.387 us; speedup vs baseline: 3.6232x; 3.6232x over previous
//
#include <hip/hip_runtime.h>
#include <math.h>

#define K 3
#define K2 9
#define BB 4
#define C 64
#define H 128
#define W 128
#define O 64
#define HW (H*W)
#define Ho 128
#define Wo 128
#define CKK 576      // C*K*K
#define TILE 64      // pixels per block (along w)
#define CG 16        // input channels per chunk / per c-group
#define NCHUNK (C/CG)   // 4

// ---------------------------------------------------------------------------
// prep_weights:
//   wT[row][o], row = (c/16)*144 + k*16 + (c%16)  <- weight[o][c][k]
//     (so the deform dot phase walks wT rows 0..575 linearly)
//   wA[tap][m], tap = c*9+ki*3+kj, m in 0..26 (18 offset ch + 9 mod ch)
// ---------------------------------------------------------------------------
__global__ void prep_weights(const float* __restrict__ weight,
                             const float* __restrict__ offset_w,
                             const float* __restrict__ mod_w,
                             float* __restrict__ wT,
                             float* __restrict__ wA)
{
    int i = blockIdx.x * blockDim.x + threadIdx.x;
    if (i < O * C * K2) {
        int k = i % K2;
        int c = (i / K2) % C;
        int o = i / (K2 * C);
        int row = (c / CG) * (CG * K2) + k * CG + (c % CG);
        wT[row * O + o] = weight[i];
    }
    if (i < CKK * 27) {
        int m = i % 27;
        int tap = i / 27;
        wA[i] = (m < 18) ? offset_w[m * CKK + tap] : mod_w[(m - 18) * CKK + tap];
    }
}

// ---------------------------------------------------------------------------
// offset_mod_kernel: one block per (b,h,64px strip). 256 threads =
// 64 px (lane) x 4 c-groups (wave). Weights read as wave-uniform s_loads.
// ---------------------------------------------------------------------------
__global__ __launch_bounds__(256) void offset_mod_kernel(
    const float* __restrict__ x,
    const float* __restrict__ wA,       // [576][27]
    const float* __restrict__ offset_b,
    const float* __restrict__ mod_b,
    float* __restrict__ offsets,        // (B,18,Ho,Wo)
    float* __restrict__ modmean)        // (B,Ho,Wo)
{
    __shared__ float red[4][TILE][27];

    int blk = blockIdx.x;
    int wt = blk % (Wo / TILE);
    int h  = (blk / (Wo / TILE)) % Ho;
    int b  = blk / ((Wo / TILE) * Ho);
    int t  = threadIdx.x;
    int px = t & 63;
    int cg = __builtin_amdgcn_readfirstlane(t >> 6);
    int w0 = wt * TILE;
    int wp = w0 + px;

    float acc[27];
    #pragma unroll
    for (int m = 0; m < 27; m++) acc[m] = 0.f;

    int yy[3]; float ymask[3];
    int xx[3]; float xmask[3];
    #pragma unroll
    for (int i = 0; i < 3; i++) {
        int y = h + i - 1;
        ymask[i] = (y >= 0 && y < H) ? 1.f : 0.f;
        yy[i] = min(max(y, 0), H - 1);
    }
    #pragma unroll
    for (int j = 0; j < 3; j++) {
        int xv = wp + j - 1;
        xmask[j] = (xv >= 0 && xv < W) ? 1.f : 0.f;
        xx[j] = min(max(xv, 0), W - 1);
    }

    const float* xb = x + ((size_t)b * C + cg * CG) * HW;
    #pragma unroll 1
    for (int c = 0; c < CG; c++) {
        const float* xc = xb + c * HW;
        #pragma unroll
        for (int i = 0; i < 3; i++) {
            #pragma unroll
            for (int j = 0; j < 3; j++) {
                float v = xc[yy[i] * W + xx[j]] * ymask[i] * xmask[j];
                const float* wrow = wA + ((cg * CG + c) * K2 + i * 3 + j) * 27;
                #pragma unroll
                for (int m = 0; m < 27; m++) acc[m] += v * wrow[m];
            }
        }
    }

    #pragma unroll
    for (int m = 0; m < 27; m++) red[cg][px][m] = acc[m];
    __syncthreads();

    if (t < TILE) {
        int p = t;
        float s[27];
        #pragma unroll
        for (int m = 0; m < 27; m++)
            s[m] = red[0][p][m] + red[1][p][m] + red[2][p][m] + red[3][p][m];
        #pragma unroll
        for (int m = 0; m < 18; m++)
            offsets[((b * 18 + m) * Ho + h) * Wo + w0 + p] = s[m] + offset_b[m];
        float sm = 0.f;
        #pragma unroll
        for (int m = 0; m < 9; m++) {
            float z = s[18 + m] + mod_b[m];
            sm += 1.f / (1.f + expf(-z));
        }
        modmean[(b * Ho + h) * Wo + w0 + p] = sm * (1.f / 9.f);
    }
}

// ---------------------------------------------------------------------------
// deform_kernel: one block per (b,h,64px strip). 256 threads.
//  phase 0: bilinear params (addr + mask-folded axis weights) -> LDS
//  per c-chunk (16 ch):
//    gather: thread=(px, quarter): 9 taps x 4 ch -> s_val[144][64]
//    dot:    thread=(px, o-group): 144 x (LDS read + 16 FMA w/ s_load weights)
//  epilogue: *modmean + bias, coalesced stores.
// ---------------------------------------------------------------------------
__global__ __launch_bounds__(256) void deform_kernel(
    const float* __restrict__ x,
    const float* __restrict__ wT,       // [576][64] reordered
    const float* __restrict__ bias,
    const float* __restrict__ offsets,  // (B,18,Ho,Wo)
    const float* __restrict__ modmean,  // (B,Ho,Wo)
    float* __restrict__ out)            // (B,O,Ho,Wo)
{
    __shared__ float s_val[CG * K2][TILE];           // 144 x 64 = 36.9 KB
    __shared__ int   s_a00[K2 * TILE];               // corner 00 plane offset
    __shared__ int   s_pk [K2 * TILE];               // bit0=dx, bit1=dy
    __shared__ float s_wy0[K2 * TILE], s_wy1[K2 * TILE];
    __shared__ float s_wx0[K2 * TILE], s_wx1[K2 * TILE];

    int blk = blockIdx.x;
    int wt = blk % (Wo / TILE);
    int h  = (blk / (Wo / TILE)) % Ho;
    int b  = blk / ((Wo / TILE) * Ho);
    int t  = threadIdx.x;
    int w0 = wt * TILE;

    // ---- phase 0: bilinear params for 9 taps x 64 px ----
    for (int e = t; e < K2 * TILE; e += 256) {
        int k = e >> 6, p = e & 63;
        int wp = w0 + p;
        float offy = offsets[((b * 18 + k) * Ho + h) * Wo + wp];
        float offx = offsets[((b * 18 + 9 + k) * Ho + h) * Wo + wp];
        float sy = (float)(h + k / 3 - 1) + offy;
        float sx = (float)(wp + k % 3 - 1) + offx;
        float fy = floorf(sy), fx = floorf(sx);
        int y0 = (int)fy, x0 = (int)fx;
        int y1 = y0 + 1, x1 = x0 + 1;
        float wy1 = sy - fy, wx1 = sx - fx;
        int y0c = min(max(y0, 0), H - 1), y1c = min(max(y1, 0), H - 1);
        int x0c = min(max(x0, 0), W - 1), x1c = min(max(x1, 0), W - 1);
        s_a00[e] = y0c * W + x0c;
        s_pk[e]  = (x1c - x0c) | ((y1c - y0c) << 1);
        s_wy0[e] = (1.f - wy1) * ((y0 >= 0 && y0 < H) ? 1.f : 0.f);
        s_wy1[e] = wy1 * ((y1 >= 0 && y1 < H) ? 1.f : 0.f);
        s_wx0[e] = (1.f - wx1) * ((x0 >= 0 && x0 < W) ? 1.f : 0.f);
        s_wx1[e] = wx1 * ((x1 >= 0 && x1 < W) ? 1.f : 0.f);
    }
    __syncthreads();

    int px = t & 63;
    int quarter = __builtin_amdgcn_readfirstlane(t >> 6);
    const float* xb = x + (size_t)b * C * HW;

    float acc[16];
    #pragma unroll
    for (int j = 0; j < 16; j++) acc[j] = 0.f;

    #pragma unroll 1
    for (int cc = 0; cc < NCHUNK; cc++) {
        if (cc) __syncthreads();   // s_val reuse vs previous dot phase

        // ---- gather: 9 taps x 4 channels per thread ----
        #pragma unroll
        for (int j = 0; j < K2; j++) {
            int e = j * 64 + px;
            int a00 = s_a00[e];
            int pk  = s_pk[e];
            float wy0 = s_wy0[e], wy1v = s_wy1[e];
            float wx0 = s_wx0[e], wx1v = s_wx1[e];
            int dx  = pk & 1;
            int dyW = (pk >> 1) * W;
            #pragma unroll
            for (int m = 0; m < 4; m++) {
                int cl = quarter + 4 * m;
                const float* xc = xb + (size_t)(cc * CG + cl) * HW;
                float v00 = xc[a00];
                float v01 = xc[a00 + dx];
                float v10 = xc[a00 + dyW];
                float v11 = xc[a00 + dyW + dx];
                float v = wy0 * (v00 * wx0 + v01 * wx1v)
                        + wy1v * (v10 * wx0 + v11 * wx1v);
                s_val[j * CG + cl][px] = v;
            }
        }
        __syncthreads();

        // ---- dot: 144 rows x 16 output channels ----
        const float* wbase = wT + (size_t)cc * (CG * K2) * O + quarter * 16;
        #pragma unroll 2
        for (int r = 0; r < CG * K2; r++) {
            float sv = s_val[r][px];
            const float* wrow = wbase + r * O;
            #pragma unroll
            for (int jj = 0; jj < 16; jj++) acc[jj] += sv * wrow[jj];
        }
    }

    // ---- epilogue ----
    float mm = modmean[(b * Ho + h) * Wo + w0 + px];
    #pragma unroll
    for (int jj = 0; jj < 16; jj++) {
        int o = quarter * 16 + jj;
        out[(((size_t)b * O + o) * Ho + h) * Wo + w0 + px] = acc[jj] * mm + bias[o];
    }
}

extern "C" void kernel_launch(void* const* d_in, const int* in_sizes, int n_in,
                              void* d_out, int out_size, void* d_ws, size_t ws_size,
                              hipStream_t stream) {
    const float* x        = (const float*)d_in[0];
    const float* weight   = (const float*)d_in[1];
    const float* bias     = (const float*)d_in[2];
    const float* offset_w = (const float*)d_in[3];
    const float* offset_b = (const float*)d_in[4];
    const float* mod_w    = (const float*)d_in[5];
    const float* mod_b    = (const float*)d_in[6];
    float* out = (float*)d_out;

    // Workspace (floats): offsets 1,179,648 | modmean 65,536 | wT 36,864 | wA 15,552
    float* ws_offsets = (float*)d_ws;
    float* ws_modmean = ws_offsets + (size_t)BB * 18 * Ho * Wo;
    float* ws_wT      = ws_modmean + (size_t)BB * Ho * Wo;
    float* ws_wA      = ws_wT + (size_t)C * K2 * O;

    prep_weights<<<(O * C * K2 + 255) / 256, 256, 0, stream>>>(
        weight, offset_w, mod_w, ws_wT, ws_wA);

    int nblk = BB * Ho * (Wo / TILE);   // 1024
    offset_mod_kernel<<<nblk, 256, 0, stream>>>(
        x, ws_wA, offset_b, mod_b, ws_offsets, ws_modmean);

    deform_kernel<<<nblk, 256, 0, stream>>>(
        x, ws_wT, bias, ws_offsets, ws_modmean, out);
}

// Round 3
// 237.414 us; speedup vs baseline: 4.5995x; 1.2695x over previous
//
#include <hip/hip_runtime.h>
#include <math.h>

#define K 3
#define K2 9
#define BB 4
#define C 64
#define H 128
#define W 128
#define O 64
#define HW (H*W)
#define Ho 128
#define Wo 128
#define TILE 64        // pixels per block (along w)
#define CG 16          // input channels per chunk
#define NCHUNK 4       // C / CG
#define KCH 144        // CG*K2 valid k per chunk
#define KPAD 160       // padded to 5 MFMA K-steps of 32
#define NSTEP 5        // KPAD/32
#define SA_STRIDE 164  // ushort stride per px row: 328B = 8B-aligned rows, 82 dwords -> ~conflict-free

typedef short short4v __attribute__((ext_vector_type(4)));
typedef short short8v __attribute__((ext_vector_type(8)));
typedef float float4v __attribute__((ext_vector_type(4)));

__device__ __forceinline__ unsigned short f2bf(float f) {
    unsigned int u = __float_as_uint(f);
    u = (u + 0x7FFF + ((u >> 16) & 1)) >> 16;   // RNE
    return (unsigned short)u;
}
__device__ __forceinline__ float bf2f(unsigned short h) {
    return __uint_as_float(((unsigned int)h) << 16);
}
__device__ __forceinline__ short8v load_frag_lds(const unsigned short* p) {
    short4v a = *(const short4v*)p;        // 8B aligned
    short4v b = *(const short4v*)(p + 4);
    return __builtin_shufflevector(a, b, 0, 1, 2, 3, 4, 5, 6, 7);
}

// ---------------------------------------------------------------------------
// prep_weights: pack conv weights into exact MFMA B-fragment order, bf16 hi/lo.
//  wB  (deform):  [cc][s][q=o-tile(4)][lane(64)][jj(8)]   k=s*32+(lane>>4)*8+jj, o=q*16+(lane&15)
//  wAB (offsets): [cc][s][jt=n-tile(2)][lane(64)][jj(8)]  n=jt*16+(lane&15) in 0..26 (18 off + 9 mod), pad 0
//  k within chunk = cl*9 + tap (cl = c%16), rows 144..159 zero-padded.
// ---------------------------------------------------------------------------
__global__ void prep_weights(const float* __restrict__ weight,
                             const float* __restrict__ offset_w,
                             const float* __restrict__ mod_w,
                             unsigned short* __restrict__ wBhi,
                             unsigned short* __restrict__ wBlo,
                             unsigned short* __restrict__ wABhi,
                             unsigned short* __restrict__ wABlo)
{
    int i = blockIdx.x * blockDim.x + threadIdx.x;
    if (i < NCHUNK * NSTEP * 4 * 64 * 8) {          // 40960
        int jj = i & 7;
        int lane = (i >> 3) & 63;
        int q = (i >> 9) & 3;
        int i2 = i >> 11;                            // cc*5 + s
        int cc = i2 / NSTEP, s = i2 % NSTEP;
        int k = s * 32 + ((lane >> 4) & 3) * 8 + jj;
        int o = q * 16 + (lane & 15);
        float wv = 0.f;
        if (k < KCH) {
            int c = cc * CG + k / 9;
            int tap = k % 9;
            wv = weight[(o * C + c) * 9 + tap];
        }
        unsigned short hi = f2bf(wv);
        wBhi[i] = hi;
        wBlo[i] = f2bf(wv - bf2f(hi));
    }
    if (i < NCHUNK * NSTEP * 2 * 64 * 8) {          // 20480
        int jj = i & 7;
        int lane = (i >> 3) & 63;
        int jt = (i >> 9) & 1;
        int i2 = i >> 10;
        int cc = i2 / NSTEP, s = i2 % NSTEP;
        int k = s * 32 + ((lane >> 4) & 3) * 8 + jj;
        int n = jt * 16 + (lane & 15);
        float wv = 0.f;
        if (k < KCH && n < 27) {
            int c = cc * CG + k / 9;
            int tap = k % 9;
            wv = (n < 18) ? offset_w[(n * C + c) * 9 + tap]
                          : mod_w[((n - 18) * C + c) * 9 + tap];
        }
        unsigned short hi = f2bf(wv);
        wABhi[i] = hi;
        wABlo[i] = f2bf(wv - bf2f(hi));
    }
}

// ---------------------------------------------------------------------------
// offset_mod_kernel: one block per (b,h,64px). 256 threads, 4 waves.
//  Per 16-ch chunk: stage 3x3 patch as bf16 hi/lo in A-frag layout -> MFMA
//  (64px x 32n, K=576) with hi/lo split. Epilogue: LDS transpose -> offsets+modmean.
// ---------------------------------------------------------------------------
__global__ __launch_bounds__(256) void offset_mod_kernel(
    const float* __restrict__ x,
    const unsigned short* __restrict__ wABhi,
    const unsigned short* __restrict__ wABlo,
    const float* __restrict__ offset_b,
    const float* __restrict__ mod_b,
    float* __restrict__ offsets,        // (B,18,Ho,Wo)
    float* __restrict__ modmean)        // (B,Ho,Wo)
{
    __shared__ unsigned short s_A[2][TILE][SA_STRIDE];   // 41,984 B
    float* s_res = (float*)&s_A[0][0][0];                // overlay [32][65] after MFMA

    int blk = blockIdx.x;
    int wt = blk % (Wo / TILE);
    int h  = (blk / (Wo / TILE)) % Ho;
    int b  = blk / ((Wo / TILE) * Ho);
    int t  = threadIdx.x;
    int px = t & 63;
    int q  = t >> 6;
    int lane = t & 63;
    int m16 = lane & 15;
    int quad = (lane >> 4) & 3;
    int w0 = wt * TILE;
    int wp = w0 + px;

    // zero the k-pad rows once (MFMA reads k 144..159; B there is 0 but avoid NaN)
    for (int z = t; z < 2 * TILE * 16; z += 256) {
        int v = z >> 10, p = (z >> 4) & 63, kk = KCH + (z & 15);
        s_A[v][p][kk] = 0;
    }

    int yy[3]; float ymask[3];
    int xx[3]; float xmask[3];
    #pragma unroll
    for (int i = 0; i < 3; i++) {
        int y = h + i - 1;
        ymask[i] = (y >= 0 && y < H) ? 1.f : 0.f;
        yy[i] = min(max(y, 0), H - 1);
        int xv = wp + i - 1;
        xmask[i] = (xv >= 0 && xv < W) ? 1.f : 0.f;
        xx[i] = min(max(xv, 0), W - 1);
    }

    float4v acc[2];
    #pragma unroll
    for (int jt = 0; jt < 2; jt++) { float4v z = {0.f,0.f,0.f,0.f}; acc[jt] = z; }

    const float* xb = x + (size_t)b * C * HW;

    #pragma unroll 1
    for (int cc = 0; cc < NCHUNK; cc++) {
        __syncthreads();
        // stage patch: thread (px,q) does 4 channels x 9 taps
        #pragma unroll
        for (int mi = 0; mi < 4; mi++) {
            int cl = q * 4 + mi;
            const float* xc = xb + (size_t)(cc * CG + cl) * HW;
            #pragma unroll
            for (int ti = 0; ti < 3; ti++) {
                #pragma unroll
                for (int tj = 0; tj < 3; tj++) {
                    float v = xc[yy[ti] * W + xx[tj]] * (ymask[ti] * xmask[tj]);
                    unsigned short hi = f2bf(v);
                    int r = cl * 9 + ti * 3 + tj;
                    s_A[0][px][r] = hi;
                    s_A[1][px][r] = f2bf(v - bf2f(hi));
                }
            }
        }
        __syncthreads();

        // MFMA: wave q owns px-tile q; n-tiles jt=0,1
        int row = q * 16 + m16;
        #pragma unroll
        for (int s = 0; s < NSTEP; s++) {
            int koff = s * 32 + quad * 8;
            short8v ahi = load_frag_lds(&s_A[0][row][koff]);
            short8v alo = load_frag_lds(&s_A[1][row][koff]);
            #pragma unroll
            for (int jt = 0; jt < 2; jt++) {
                int idx = (((cc * NSTEP + s) * 2 + jt) * 64 + lane) * 8;
                short8v bhi = *(const short8v*)(wABhi + idx);
                short8v blo = *(const short8v*)(wABlo + idx);
                acc[jt] = __builtin_amdgcn_mfma_f32_16x16x32_bf16(ahi, bhi, acc[jt], 0, 0, 0);
                acc[jt] = __builtin_amdgcn_mfma_f32_16x16x32_bf16(alo, bhi, acc[jt], 0, 0, 0);
                acc[jt] = __builtin_amdgcn_mfma_f32_16x16x32_bf16(ahi, blo, acc[jt], 0, 0, 0);
            }
        }
    }

    // epilogue: C layout col=lane&15 (n), row=(lane>>4)*4+reg (px-in-tile)
    __syncthreads();
    #pragma unroll
    for (int jt = 0; jt < 2; jt++) {
        #pragma unroll
        for (int r = 0; r < 4; r++) {
            int n = jt * 16 + m16;
            int pr = q * 16 + quad * 4 + r;
            s_res[n * 65 + pr] = acc[jt][r];
        }
    }
    __syncthreads();
    if (t < TILE) {
        int p = t;
        #pragma unroll
        for (int m = 0; m < 18; m++)
            offsets[((b * 18 + m) * Ho + h) * Wo + w0 + p] = s_res[m * 65 + p] + offset_b[m];
        float sm = 0.f;
        #pragma unroll
        for (int m = 0; m < 9; m++) {
            float z = s_res[(18 + m) * 65 + p] + mod_b[m];
            sm += 1.f / (1.f + expf(-z));
        }
        modmean[(b * Ho + h) * Wo + w0 + p] = sm * (1.f / 9.f);
    }
}

// ---------------------------------------------------------------------------
// deform_kernel: one block per (b,h,64px). 256 threads, 4 waves.
//  phase 0: packed bilinear params -> LDS
//  per chunk: gather bilinear samples as bf16 hi/lo in A-frag layout,
//             MFMA 64px x 64o with hi/lo split (wave q owns o-tile q).
//  epilogue: LDS transpose -> coalesced stores.
// ---------------------------------------------------------------------------
__global__ __launch_bounds__(256) void deform_kernel(
    const float* __restrict__ x,
    const unsigned short* __restrict__ wBhi,
    const unsigned short* __restrict__ wBlo,
    const float* __restrict__ bias,
    const float* __restrict__ offsets,
    const float* __restrict__ modmean,
    float* __restrict__ out)
{
    __shared__ unsigned short s_A[2][TILE][SA_STRIDE];   // 41,984 B
    __shared__ float4v s_wgt[K2 * TILE];                 // 9,216 B (wy0,wy1,wx0,wx1 mask-folded)
    __shared__ unsigned int s_ai[K2 * TILE];             // 2,304 B (a00 | dx<<14 | dy<<15)
    float* s_out = (float*)&s_A[0][0][0];                // overlay [64][65] after MFMA

    int blk = blockIdx.x;
    int wt = blk % (Wo / TILE);
    int h  = (blk / (Wo / TILE)) % Ho;
    int b  = blk / ((Wo / TILE) * Ho);
    int t  = threadIdx.x;
    int px = t & 63;
    int q  = t >> 6;
    int lane = t & 63;
    int m16 = lane & 15;
    int quad = (lane >> 4) & 3;
    int w0 = wt * TILE;

    // phase 0: bilinear params for 9 taps x 64 px
    for (int e = t; e < K2 * TILE; e += 256) {
        int k = e >> 6, p = e & 63;
        int wp = w0 + p;
        float offy = offsets[((b * 18 + k) * Ho + h) * Wo + wp];
        float offx = offsets[((b * 18 + 9 + k) * Ho + h) * Wo + wp];
        float sy = (float)(h + k / 3 - 1) + offy;
        float sx = (float)(wp + k % 3 - 1) + offx;
        float fy = floorf(sy), fx = floorf(sx);
        int y0 = (int)fy, x0 = (int)fx;
        float wy1 = sy - fy, wx1 = sx - fx;
        int y0c = min(max(y0, 0), H - 1), y1c = min(max(y0 + 1, 0), H - 1);
        int x0c = min(max(x0, 0), W - 1), x1c = min(max(x0 + 1, 0), W - 1);
        s_ai[e] = (unsigned int)(y0c * W + x0c)
                | ((unsigned int)(x1c - x0c) << 14)
                | ((unsigned int)(y1c - y0c) << 15);
        float4v wg;
        wg[0] = (1.f - wy1) * ((y0 >= 0 && y0 < H) ? 1.f : 0.f);
        wg[1] = wy1 * ((y0 + 1 >= 0 && y0 + 1 < H) ? 1.f : 0.f);
        wg[2] = (1.f - wx1) * ((x0 >= 0 && x0 < W) ? 1.f : 0.f);
        wg[3] = wx1 * ((x0 + 1 >= 0 && x0 + 1 < W) ? 1.f : 0.f);
        s_wgt[e] = wg;
    }
    // zero k-pad rows
    for (int z = t; z < 2 * TILE * 16; z += 256) {
        int v = z >> 10, p = (z >> 4) & 63, kk = KCH + (z & 15);
        s_A[v][p][kk] = 0;
    }

    float4v acc[4];
    #pragma unroll
    for (int i = 0; i < 4; i++) { float4v z = {0.f,0.f,0.f,0.f}; acc[i] = z; }

    const float* xb = x + (size_t)b * C * HW;

    #pragma unroll 1
    for (int cc = 0; cc < NCHUNK; cc++) {
        __syncthreads();
        // gather: thread (px,q): 9 taps x 4 channels
        #pragma unroll
        for (int j = 0; j < K2; j++) {
            int e = j * 64 + px;
            unsigned int ai = s_ai[e];
            float4v wg = s_wgt[e];
            int a00 = ai & 0x3FFF;
            int dx  = (ai >> 14) & 1;
            int dyW = ((ai >> 15) & 1) * W;
            #pragma unroll
            for (int mi = 0; mi < 4; mi++) {
                int cl = q * 4 + mi;
                const float* xc = xb + (size_t)(cc * CG + cl) * HW;
                float v00 = xc[a00];
                float v01 = xc[a00 + dx];
                float v10 = xc[a00 + dyW];
                float v11 = xc[a00 + dyW + dx];
                float v = wg[0] * (v00 * wg[2] + v01 * wg[3])
                        + wg[1] * (v10 * wg[2] + v11 * wg[3]);
                unsigned short hi = f2bf(v);
                int r = cl * 9 + j;
                s_A[0][px][r] = hi;
                s_A[1][px][r] = f2bf(v - bf2f(hi));
            }
        }
        __syncthreads();

        // MFMA: wave q owns o-tile q; px-tiles i=0..3
        #pragma unroll
        for (int s = 0; s < NSTEP; s++) {
            int idx = (((cc * NSTEP + s) * 4 + q) * 64 + lane) * 8;
            short8v bhi = *(const short8v*)(wBhi + idx);
            short8v blo = *(const short8v*)(wBlo + idx);
            int koff = s * 32 + quad * 8;
            #pragma unroll
            for (int i = 0; i < 4; i++) {
                int row = i * 16 + m16;
                short8v ahi = load_frag_lds(&s_A[0][row][koff]);
                short8v alo = load_frag_lds(&s_A[1][row][koff]);
                acc[i] = __builtin_amdgcn_mfma_f32_16x16x32_bf16(ahi, bhi, acc[i], 0, 0, 0);
                acc[i] = __builtin_amdgcn_mfma_f32_16x16x32_bf16(alo, bhi, acc[i], 0, 0, 0);
                acc[i] = __builtin_amdgcn_mfma_f32_16x16x32_bf16(ahi, blo, acc[i], 0, 0, 0);
            }
        }
    }

    // epilogue: transpose via LDS, then coalesced stores
    __syncthreads();
    #pragma unroll
    for (int i = 0; i < 4; i++) {
        #pragma unroll
        for (int r = 0; r < 4; r++) {
            int o = q * 16 + m16;                  // col = o-in-tile
            int pr = i * 16 + quad * 4 + r;        // row = px-in-tile
            s_out[o * 65 + pr] = acc[i][r];
        }
    }
    __syncthreads();
    {
        float mm = modmean[(b * Ho + h) * Wo + w0 + px];
        #pragma unroll
        for (int jj = 0; jj < 16; jj++) {
            int o = q * 16 + jj;
            out[(((size_t)b * O + o) * Ho + h) * Wo + w0 + px] =
                s_out[o * 65 + px] * mm + bias[o];
        }
    }
}

extern "C" void kernel_launch(void* const* d_in, const int* in_sizes, int n_in,
                              void* d_out, int out_size, void* d_ws, size_t ws_size,
                              hipStream_t stream) {
    const float* x        = (const float*)d_in[0];
    const float* weight   = (const float*)d_in[1];
    const float* bias     = (const float*)d_in[2];
    const float* offset_w = (const float*)d_in[3];
    const float* offset_b = (const float*)d_in[4];
    const float* mod_w    = (const float*)d_in[5];
    const float* mod_b    = (const float*)d_in[6];
    float* out = (float*)d_out;

    // Workspace: offsets 1,179,648 f | modmean 65,536 f | wB hi/lo 2x40,960 us | wAB hi/lo 2x20,480 us
    float* ws_offsets = (float*)d_ws;
    float* ws_modmean = ws_offsets + (size_t)BB * 18 * Ho * Wo;
    unsigned short* wBhi  = (unsigned short*)(ws_modmean + (size_t)BB * Ho * Wo);
    unsigned short* wBlo  = wBhi + 40960;
    unsigned short* wABhi = wBlo + 40960;
    unsigned short* wABlo = wABhi + 20480;

    prep_weights<<<160, 256, 0, stream>>>(weight, offset_w, mod_w, wBhi, wBlo, wABhi, wABlo);

    int nblk = BB * Ho * (Wo / TILE);   // 1024
    offset_mod_kernel<<<nblk, 256, 0, stream>>>(
        x, wABhi, wABlo, offset_b, mod_b, ws_offsets, ws_modmean);

    deform_kernel<<<nblk, 256, 0, stream>>>(
        x, wBhi, wBlo, bias, ws_offsets, ws_modmean, out);
}

// Round 4
// 199.945 us; speedup vs baseline: 5.4614x; 1.1874x over previous
//
#include <hip/hip_runtime.h>
#include <math.h>

#define K 3
#define K2 9
#define BB 4
#define C 64
#define H 128
#define W 128
#define O 64
#define HW (H*W)
#define Ho 128
#define Wo 128
#define TILE 64        // pixels per block (along w)
#define CG 16          // input channels per chunk
#define NCHUNK 4       // C / CG
#define KCH 144        // CG*K2 valid k per chunk
#define NSTEP 5        // ceil(KCH/32) K-steps of 32
#define SA_STRIDE 164  // _Float16 per px row (328 B): 160 used + 4 slack

typedef _Float16 half4v __attribute__((ext_vector_type(4)));
typedef _Float16 half8v __attribute__((ext_vector_type(8)));
typedef float float4v __attribute__((ext_vector_type(4)));

__device__ __forceinline__ half8v load_frag_lds(const _Float16* p) {
    half4v a = *(const half4v*)p;        // 8B-aligned (koff multiple of 8)
    half4v b = *(const half4v*)(p + 4);
    return __builtin_shufflevector(a, b, 0, 1, 2, 3, 4, 5, 6, 7);
}

// ---------------------------------------------------------------------------
// prep_weights: pack conv weights into MFMA B-fragment order, fp16.
//  wB  (main conv): [cc][s][q=o-tile(4)][lane(64)][jj(8)]
//       k = s*32+(lane>>4)*8+jj (k = cl*9+tap within chunk), o = q*16+(lane&15)
//  wAB (offset+mod): [cc][s][jt=n-tile(2)][lane(64)][jj(8)], n = jt*16+(lane&15)
//       n in 0..26 = 18 offset ch then 9 mod ch; k>=144 or n>=27 -> 0
// ---------------------------------------------------------------------------
__global__ void prep_weights(const float* __restrict__ weight,
                             const float* __restrict__ offset_w,
                             const float* __restrict__ mod_w,
                             _Float16* __restrict__ wB,
                             _Float16* __restrict__ wAB)
{
    int i = blockIdx.x * blockDim.x + threadIdx.x;
    if (i < NCHUNK * NSTEP * 4 * 64 * 8) {          // 40960
        int jj = i & 7;
        int lane = (i >> 3) & 63;
        int q = (i >> 9) & 3;
        int i2 = i >> 11;                            // cc*NSTEP + s
        int cc = i2 / NSTEP, s = i2 % NSTEP;
        int k = s * 32 + ((lane >> 4) & 3) * 8 + jj;
        int o = q * 16 + (lane & 15);
        float wv = 0.f;
        if (k < KCH) {
            int c = cc * CG + k / 9;
            int tap = k % 9;
            wv = weight[(o * C + c) * 9 + tap];
        }
        wB[i] = (_Float16)wv;
    }
    if (i < NCHUNK * NSTEP * 2 * 64 * 8) {          // 20480
        int jj = i & 7;
        int lane = (i >> 3) & 63;
        int jt = (i >> 9) & 1;
        int i2 = i >> 10;
        int cc = i2 / NSTEP, s = i2 % NSTEP;
        int k = s * 32 + ((lane >> 4) & 3) * 8 + jj;
        int n = jt * 16 + (lane & 15);
        float wv = 0.f;
        if (k < KCH && n < 27) {
            int c = cc * CG + k / 9;
            int tap = k % 9;
            wv = (n < 18) ? offset_w[(n * C + c) * 9 + tap]
                          : mod_w[((n - 18) * C + c) * 9 + tap];
        }
        wAB[i] = (_Float16)wv;
    }
}

// ---------------------------------------------------------------------------
// fused_kernel: one block per (b,h,64px strip), 256 threads, 4 waves.
//  A: offset/mod conv via MFMA (64px x 27n, K=576) -> s_res in LDS
//  B: bilinear params (packed addr + mask-folded weights) + modmean -> LDS
//  C: per 16-ch chunk: bilinear gather -> fp16 A-frag LDS -> MFMA 64px x 64o
//  epilogue: LDS transpose -> coalesced stores.
// ---------------------------------------------------------------------------
__global__ __launch_bounds__(256, 4) void fused_kernel(
    const float* __restrict__ x,
    const _Float16* __restrict__ wB,
    const _Float16* __restrict__ wAB,
    const float* __restrict__ bias,
    const float* __restrict__ offset_b,
    const float* __restrict__ mod_b,
    float* __restrict__ out)
{
    __shared__ _Float16 s_A[TILE][SA_STRIDE];   // 20,992 B (A-frags; out overlay)
    __shared__ unsigned int s_ai[K2 * TILE];    //  2,304 B (a00 | dx<<14 | dy<<15)
    __shared__ float4v s_wgt[K2 * TILE];        //  9,216 B (wy0,wy1,wx0,wx1)
    __shared__ float s_res[27 * 65];            //  7,020 B (offset/mod conv result)
    __shared__ float s_mm[TILE];                //    256 B (mod mean per px)
    float* s_out = (float*)&s_A[0][0];          // overlay [64][65] after phase C

    int blk = blockIdx.x;
    int wt = blk % (Wo / TILE);
    int h  = (blk / (Wo / TILE)) % Ho;
    int b  = blk / ((Wo / TILE) * Ho);
    int t  = threadIdx.x;
    int px = t & 63;
    int q  = t >> 6;
    int lane = t & 63;
    int m16 = lane & 15;
    int quad = (lane >> 4) & 3;
    int w0 = wt * TILE;
    int wp = w0 + px;

    // zero k-pad rows 144..159 (persist across both MFMA phases)
    for (int z = t; z < TILE * 16; z += 256)
        s_A[z >> 4][KCH + (z & 15)] = (_Float16)0.f;

    // patch geometry (regs, reused across phase-A chunks)
    int yy[3]; float ymask[3];
    int xx[3]; float xmask[3];
    #pragma unroll
    for (int i = 0; i < 3; i++) {
        int y = h + i - 1;
        ymask[i] = (y >= 0 && y < H) ? 1.f : 0.f;
        yy[i] = min(max(y, 0), H - 1);
        int xv = wp + i - 1;
        xmask[i] = (xv >= 0 && xv < W) ? 1.f : 0.f;
        xx[i] = min(max(xv, 0), W - 1);
    }

    const float* xb = x + (size_t)b * C * HW;

    // ================= phase A: offset/mod conv =================
    float4v acc2[2];
    #pragma unroll
    for (int jt = 0; jt < 2; jt++) { float4v z = {0.f,0.f,0.f,0.f}; acc2[jt] = z; }

    #pragma unroll 1
    for (int cc = 0; cc < NCHUNK; cc++) {
        __syncthreads();
        #pragma unroll
        for (int mi = 0; mi < 4; mi++) {
            int cl = q * 4 + mi;
            const float* xc = xb + (size_t)(cc * CG + cl) * HW;
            #pragma unroll
            for (int ti = 0; ti < 3; ti++) {
                #pragma unroll
                for (int tj = 0; tj < 3; tj++) {
                    float v = xc[yy[ti] * W + xx[tj]] * (ymask[ti] * xmask[tj]);
                    s_A[px][cl * 9 + ti * 3 + tj] = (_Float16)v;
                }
            }
        }
        __syncthreads();

        int row = q * 16 + m16;
        #pragma unroll
        for (int s = 0; s < NSTEP; s++) {
            int koff = s * 32 + quad * 8;
            half8v af = load_frag_lds(&s_A[row][koff]);
            #pragma unroll
            for (int jt = 0; jt < 2; jt++) {
                int idx = (((cc * NSTEP + s) * 2 + jt) * 64 + lane) * 8;
                half8v bf = *(const half8v*)(wAB + idx);
                acc2[jt] = __builtin_amdgcn_mfma_f32_16x16x32_f16(af, bf, acc2[jt], 0, 0, 0);
            }
        }
    }
    __syncthreads();
    // C layout: col(n) = lane&15, row(px-in-tile) = quad*4+reg; wave q owns px-tile q
    #pragma unroll
    for (int jt = 0; jt < 2; jt++) {
        int n = jt * 16 + m16;
        if (n < 27) {
            #pragma unroll
            for (int r = 0; r < 4; r++)
                s_res[n * 65 + q * 16 + quad * 4 + r] = acc2[jt][r];
        }
    }
    __syncthreads();

    // ================= phase B: bilinear params + modmean =================
    #pragma unroll
    for (int ee = 0; ee < 3; ee++) {
        int e = t + ee * 256;
        if (e < K2 * TILE) {
            int k = e >> 6, p = e & 63;
            float offy = s_res[k * 65 + p] + offset_b[k];
            float offx = s_res[(9 + k) * 65 + p] + offset_b[9 + k];
            float sy = (float)(h + k / 3 - 1) + offy;
            float sx = (float)(w0 + p + k % 3 - 1) + offx;
            float fy = floorf(sy), fx = floorf(sx);
            int y0 = (int)fy, x0 = (int)fx;
            float wy1 = sy - fy, wx1 = sx - fx;
            int y0c = min(max(y0, 0), H - 1), y1c = min(max(y0 + 1, 0), H - 1);
            int x0c = min(max(x0, 0), W - 1), x1c = min(max(x0 + 1, 0), W - 1);
            s_ai[e] = (unsigned int)(y0c * W + x0c)
                    | ((unsigned int)(x1c - x0c) << 14)
                    | ((unsigned int)(y1c - y0c) << 15);
            float4v wg;
            wg[0] = (1.f - wy1) * ((y0 >= 0 && y0 < H) ? 1.f : 0.f);
            wg[1] = wy1 * ((y0 + 1 >= 0 && y0 + 1 < H) ? 1.f : 0.f);
            wg[2] = (1.f - wx1) * ((x0 >= 0 && x0 < W) ? 1.f : 0.f);
            wg[3] = wx1 * ((x0 + 1 >= 0 && x0 + 1 < W) ? 1.f : 0.f);
            s_wgt[e] = wg;
        }
    }
    if (t < TILE) {
        float sm = 0.f;
        #pragma unroll
        for (int m = 0; m < 9; m++) {
            float z = s_res[(18 + m) * 65 + t] + mod_b[m];
            sm += 1.f / (1.f + expf(-z));
        }
        s_mm[t] = sm * (1.f / 9.f);
    }

    // ================= phase C: gather + main MFMA =================
    float4v acc[4];
    #pragma unroll
    for (int i = 0; i < 4; i++) { float4v z = {0.f,0.f,0.f,0.f}; acc[i] = z; }

    #pragma unroll 1
    for (int cc = 0; cc < NCHUNK; cc++) {
        __syncthreads();
        #pragma unroll
        for (int j = 0; j < K2; j++) {
            int e = j * 64 + px;
            unsigned int ai = s_ai[e];
            float4v wg = s_wgt[e];
            int a00 = ai & 0x3FFF;
            int dx  = (ai >> 14) & 1;
            int dyW = ((ai >> 15) & 1) * W;
            #pragma unroll
            for (int mi = 0; mi < 4; mi++) {
                int cl = q * 4 + mi;
                const float* xc = xb + (size_t)(cc * CG + cl) * HW;
                float v00 = xc[a00];
                float v01 = xc[a00 + dx];
                float v10 = xc[a00 + dyW];
                float v11 = xc[a00 + dyW + dx];
                float v = wg[0] * (v00 * wg[2] + v01 * wg[3])
                        + wg[1] * (v10 * wg[2] + v11 * wg[3]);
                s_A[px][cl * 9 + j] = (_Float16)v;
            }
        }
        __syncthreads();

        // wave q owns o-tile q; px-tiles i = 0..3
        #pragma unroll
        for (int s = 0; s < NSTEP; s++) {
            int idx = (((cc * NSTEP + s) * 4 + q) * 64 + lane) * 8;
            half8v bf = *(const half8v*)(wB + idx);
            int koff = s * 32 + quad * 8;
            #pragma unroll
            for (int i = 0; i < 4; i++) {
                half8v af = load_frag_lds(&s_A[i * 16 + m16][koff]);
                acc[i] = __builtin_amdgcn_mfma_f32_16x16x32_f16(af, bf, acc[i], 0, 0, 0);
            }
        }
    }

    // ================= epilogue =================
    __syncthreads();
    #pragma unroll
    for (int i = 0; i < 4; i++) {
        int o = q * 16 + m16;
        #pragma unroll
        for (int r = 0; r < 4; r++)
            s_out[o * 65 + i * 16 + quad * 4 + r] = acc[i][r];
    }
    __syncthreads();
    {
        float mm = s_mm[px];
        #pragma unroll
        for (int jj = 0; jj < 16; jj++) {
            int o = q * 16 + jj;
            out[(((size_t)b * O + o) * Ho + h) * Wo + w0 + px] =
                s_out[o * 65 + px] * mm + bias[o];
        }
    }
}

extern "C" void kernel_launch(void* const* d_in, const int* in_sizes, int n_in,
                              void* d_out, int out_size, void* d_ws, size_t ws_size,
                              hipStream_t stream) {
    const float* x        = (const float*)d_in[0];
    const float* weight   = (const float*)d_in[1];
    const float* bias     = (const float*)d_in[2];
    const float* offset_w = (const float*)d_in[3];
    const float* offset_b = (const float*)d_in[4];
    const float* mod_w    = (const float*)d_in[5];
    const float* mod_b    = (const float*)d_in[6];
    float* out = (float*)d_out;

    _Float16* wB  = (_Float16*)d_ws;            // 40960 halves
    _Float16* wAB = wB + 40960;                 // 20480 halves

    prep_weights<<<160, 256, 0, stream>>>(weight, offset_w, mod_w, wB, wAB);

    int nblk = BB * Ho * (Wo / TILE);   // 1024 = 4 per CU, all co-resident
    fused_kernel<<<nblk, 256, 0, stream>>>(
        x, wB, wAB, bias, offset_b, mod_b, out);
}